// Round 10
// baseline (436.108 us; speedup 1.0000x reference)
//
#include <hip/hip_runtime.h>
#include <hip/hip_bf16.h>

#define N 512
#define CS 1024
#define CZ 128
#define H 12
#define HD 16
#define KC 2112   // final gemm K (cat width)

// ---------------------------------------------------------------------------
// dtype sniff: 1 if buffer holds f32, 0 if bf16. Reads 32 16-bit words.
// ---------------------------------------------------------------------------
__device__ int sniff_f32(const unsigned short* p) {
    int bad = 0;
    for (int i = 0; i < 32; ++i) {
        unsigned short u = p[i];
        int e = (u >> 7) & 0xFF;
        if (e == 0xFF || e >= 141 || (e <= 27 && (u & 0x7FFFu) != 0)) bad++;
    }
    return bad > 0;
}

__device__ __forceinline__ float ld(const void* p, int i, int f32) {
    return f32 ? ((const float*)p)[i]
               : __bfloat162float(((const __hip_bfloat16*)p)[i]);
}

__device__ __forceinline__ float bfu(unsigned short u) {
    return __bfloat162float(*(const __hip_bfloat16*)&u);
}

// ---------------------------------------------------------------------------
// split-precision helpers for f32-accurate bf16 MFMA:
// x = hi + lo (hi = bf16(x), lo = bf16(x-hi)); A*B = Ah*Bh + Ah*Bl + Al*Bh.
// ---------------------------------------------------------------------------
typedef __attribute__((ext_vector_type(8))) short bf16x8;
typedef __attribute__((ext_vector_type(4))) float f32x4;
typedef __attribute__((ext_vector_type(8))) unsigned short u16x8;

// returns hi bf16 in low 16 bits, lo bf16 in high 16 bits
__device__ __forceinline__ unsigned int split_bf16(float x) {
    __hip_bfloat16 hb = __float2bfloat16(x);
    float hf = __bfloat162float(hb);
    __hip_bfloat16 lb = __float2bfloat16(x - hf);
    unsigned int h = *reinterpret_cast<unsigned short*>(&hb);
    unsigned int l = *reinterpret_cast<unsigned short*>(&lb);
    return h | (l << 16);
}

__device__ __forceinline__ void wcat_resolve(int col,
        const void* Wq, const void* Wkv, const void* Wqp, const void* Wkvp,
        const void*& W, int& cc, int& ldim) {
    if (col < 192)      { W = Wq;   cc = col;       ldim = 192; }
    else if (col < 576) { W = Wkv;  cc = col - 192; ldim = 384; }
    else if (col < 720) { W = Wqp;  cc = col - 576; ldim = 144; }
    else                { W = Wkvp; cc = col - 720; ldim = 432; }
}

// ---------------------------------------------------------------------------
// K0: prep_w — transpose + hi/lo-split weights, and hi/lo-split s.
// WcatT_h/l [1152 cols][1024 k], WoutT_h/l [1024 cols][2112 k] (transposed);
// sH/sL [512][1024] (row-major, no transpose).
// grid: 1152 + 2112 + 512 = 3776 blocks x 256 thr.
// ---------------------------------------------------------------------------
__global__ void prep_w(const void* Wq, const void* Wkv, const void* Wqp,
                       const void* Wkvp, const void* Wout, const void* s,
                       unsigned short* WcTh, unsigned short* WcTl,
                       unsigned short* WoTh, unsigned short* WoTl,
                       unsigned short* sH, unsigned short* sL)
{
    __shared__ unsigned short th[32][33], tl[32][33];
    __shared__ int flag;
    int t = threadIdx.x;                 // 256
    if (t == 0) flag = sniff_f32((const unsigned short*)s);
    __syncthreads();
    int f32 = flag;
    int tx = t & 31, ty = t >> 5;        // ty 0..7
    int b = blockIdx.x;
    if (b < 1152) {
        int ct = b % 36, kt = b / 36;
        int c0 = ct * 32, k0 = kt * 32;
        #pragma unroll
        for (int r = 0; r < 4; ++r) {
            int k = k0 + ty + 8 * r, c = c0 + tx;
            const void* W; int cc, ldim;
            wcat_resolve(c, Wq, Wkv, Wqp, Wkvp, W, cc, ldim);
            unsigned int pe = split_bf16(ld(W, k * ldim + cc, f32));
            th[ty + 8 * r][tx] = (unsigned short)pe;
            tl[ty + 8 * r][tx] = (unsigned short)(pe >> 16);
        }
        __syncthreads();
        #pragma unroll
        for (int r = 0; r < 4; ++r) {
            int c = c0 + ty + 8 * r, k = k0 + tx;
            WcTh[c * CS + k] = th[tx][ty + 8 * r];
            WcTl[c * CS + k] = tl[tx][ty + 8 * r];
        }
    } else if (b < 3264) {
        int bb = b - 1152;
        int ct = bb & 31, kt = bb >> 5;   // 32 col tiles x 66 k tiles
        int c0 = ct * 32, k0 = kt * 32;
        #pragma unroll
        for (int r = 0; r < 4; ++r) {
            int k = k0 + ty + 8 * r, c = c0 + tx;
            unsigned int pe = split_bf16(ld(Wout, k * CS + c, f32));
            th[ty + 8 * r][tx] = (unsigned short)pe;
            tl[ty + 8 * r][tx] = (unsigned short)(pe >> 16);
        }
        __syncthreads();
        #pragma unroll
        for (int r = 0; r < 4; ++r) {
            int c = c0 + ty + 8 * r, k = k0 + tx;
            WoTh[c * KC + k] = th[tx][ty + 8 * r];
            WoTl[c * KC + k] = tl[tx][ty + 8 * r];
        }
    } else {
        // s split (no transpose): 16 row-tiles x 32 col-tiles of 32x32
        int bb = b - 3264;
        int rt = bb >> 5, ct = bb & 31;
        #pragma unroll
        for (int r = 0; r < 4; ++r) {
            int row = rt * 32 + ty + 8 * r, col = ct * 32 + tx;
            unsigned int pe = split_bf16(ld(s, row * CS + col, f32));
            sH[row * CS + col] = (unsigned short)pe;
            sL[row * CS + col] = (unsigned short)(pe >> 16);
        }
    }
}

// ---------------------------------------------------------------------------
// K1: proj_gemm — rawP = s @ Wcat (512 x 1152, K=1024), pure load+MFMA.
// Tile 16x64: 4 waves, wave w = cols w*16..w*16+15. No LDS, no barriers,
// no VALU in K-loop. Grid (18,32) = 576 blocks ≈ 2.25 blocks/CU.
// ---------------------------------------------------------------------------
__global__ void proj_gemm(const unsigned short* sH, const unsigned short* sL,
                          const unsigned short* BTh, const unsigned short* BTl,
                          float* rawP)
{
    int t = threadIdx.x;               // 256
    int bn = blockIdx.x;               // 18 col tiles of 64
    int bm = blockIdx.y;               // 32 row tiles of 16
    int w  = t >> 6, l = t & 63;
    int lr = l & 15, lq = l >> 4;

    int arow = bm * 16 + lr;
    int bcol = bn * 64 + w * 16 + lr;
    const unsigned short* ah_p = sH + arow * CS;
    const unsigned short* al_p = sL + arow * CS;
    const unsigned short* bh_p = BTh + bcol * CS;
    const unsigned short* bl_p = BTl + bcol * CS;

    f32x4 acc = {0.f, 0.f, 0.f, 0.f};
    #pragma unroll 4
    for (int kt = 0; kt < CS / 32; ++kt) {
        int kk = kt * 32 + lq * 8;
        bf16x8 a_h = *(const bf16x8*)(ah_p + kk);
        bf16x8 a_l = *(const bf16x8*)(al_p + kk);
        bf16x8 b_h = *(const bf16x8*)(bh_p + kk);
        bf16x8 b_l = *(const bf16x8*)(bl_p + kk);
        acc = __builtin_amdgcn_mfma_f32_16x16x32_bf16(a_h, b_h, acc, 0, 0, 0);
        acc = __builtin_amdgcn_mfma_f32_16x16x32_bf16(a_h, b_l, acc, 0, 0, 0);
        acc = __builtin_amdgcn_mfma_f32_16x16x32_bf16(a_l, b_h, acc, 0, 0, 0);
    }

    int row0 = bm * 16 + lq * 4;
    #pragma unroll
    for (int r = 0; r < 4; ++r)
        rawP[(row0 + r) * 1152 + bcol] = acc[r];
}

// ---------------------------------------------------------------------------
// K2: proj_post — bias add + q/k/v scatter + point rotation.
// k and kp stored TRANSPOSED (kT[192][512], kpT[144][512]).
// ---------------------------------------------------------------------------
__global__ void proj_post(const float* rawP,
                          const void* bq, const void* bkv,
                          const void* bqp, const void* bkvp,
                          const void* rot, const void* trans, const void* s,
                          float* q, float* kT, float* v,
                          float* qp, float* kpT, float* vp)
{
    __shared__ float rawL[576];
    __shared__ float R[9], T[3];
    __shared__ int flag;
    int t = threadIdx.x;     // 576
    int i = blockIdx.x;
    if (t == 0) flag = sniff_f32((const unsigned short*)s);
    __syncthreads();
    int f32 = flag;

    // qkv scatter
    {
        float val = rawP[i * 1152 + t];
        if (t < 192) q[i * 192 + t] = val + ld(bq, t, f32);
        else {
            int cc = t - 192;
            float vv = val + ld(bkv, cc, f32);
            int h = cc >> 5, t2 = cc & 31;
            if (t2 < 16) kT[(h * 16 + t2) * 512 + i] = vv;
            else         v[i * 192 + h * 16 + (t2 - 16)] = vv;
        }
    }
    // points: bias + stage
    rawL[t] = rawP[i * 1152 + 576 + t]
            + (t < 144 ? ld(bqp, t, f32) : ld(bkvp, t - 144, f32));
    if (t < 9) R[t] = ld(rot, i * 9 + t, f32);
    if (t >= 16 && t < 19) T[t - 16] = ld(trans, i * 3 + (t - 16), f32);
    __syncthreads();
    if (t < 192) {
        float x, y, zc;
        if (t < 48) { x = rawL[t];        y = rawL[48 + t];   zc = rawL[96 + t]; }
        else { int pk = t - 48;
               x = rawL[144 + pk]; y = rawL[288 + pk]; zc = rawL[432 + pk]; }
        float rx = R[0]*x + R[1]*y + R[2]*zc + T[0];
        float ry = R[3]*x + R[4]*y + R[5]*zc + T[1];
        float rz = R[6]*x + R[7]*y + R[8]*zc + T[2];
        if (t < 48) {
            int h = t >> 2, pp = t & 3, b = i * 144 + h * 12 + pp * 3;
            qp[b] = rx; qp[b + 1] = ry; qp[b + 2] = rz;
        } else {
            int pk = t - 48, h = pk / 12, idx = pk % 12;
            if (idx < 4) {
                int row = h * 12 + idx * 3;
                kpT[(row + 0) * 512 + i] = rx;
                kpT[(row + 1) * 512 + i] = ry;
                kpT[(row + 2) * 512 + i] = rz;
            } else {
                int b = i * 288 + h * 24 + (idx - 4) * 3;
                vp[b] = rx; vp[b + 1] = ry; vp[b + 2] = rz;
            }
        }
    }
}

// ---------------------------------------------------------------------------
// K3: fused bias + logits + softmax + (o, o_pt, o_pair) per query row i.
// Phase A z-tiles REGISTER-PREFETCHED (issue next tile's loads before
// computing current -> HBM latency hides under the 128-FMA compute).
// cat written as pre-split bf16 pairs (catH/catL) - exactly the values
// final_gemm's in-loop split produced before -> bit-identical output.
// ---------------------------------------------------------------------------
__global__ void attn_fused(const float* q, const float* kT, const float* v,
                           const float* qp, const float* kpT, const float* vp,
                           const void* z, const void* Wb, const void* bb,
                           const void* head_w, const void* mask,
                           const void* rot, const void* trans, const void* s,
                           unsigned short* catH, unsigned short* catL)
{
    __shared__ float attL[H * N];        // 24 KB
    __shared__ float WbL[CZ * H];        // 6 KB
    __shared__ float U[6144];            // 24 KB: zT tile (32x132) / pairP
    __shared__ float qL[192], qpL[144];
    __shared__ float RL[9], TL[3], bbL[H], hwL[H];
    __shared__ float miS;
    __shared__ int flag;
    int t = threadIdx.x;   // 512
    int i = blockIdx.x;
    if (t == 0) flag = sniff_f32((const unsigned short*)s);
    __syncthreads();
    int f32 = flag;
    for (int idx = t; idx < CZ * H; idx += 512) WbL[idx] = ld(Wb, idx, f32);
    if (t < 192) qL[t] = q[i * 192 + t];
    else if (t < 336) qpL[t - 192] = qp[i * 144 + (t - 192)];
    else if (t < 345) RL[t - 336] = ld(rot, i * 9 + (t - 336), f32);
    else if (t < 348) TL[t - 345] = ld(trans, i * 3 + (t - 345), f32);
    else if (t < 360) bbL[t - 348] = ld(bb, t - 348, f32);
    else if (t < 372) {
        float x = ld(head_w, t - 360, f32);
        float sp = (x > 20.f) ? x : log1pf(expf(x));
        hwL[t - 360] = sp * 0.13608276348795434f;   // softplus * sqrt(1/54)
    }
    else if (t == 372) miS = ld(mask, i, f32);
    __syncthreads();

    // ---- Phase A: bias b = bb + z[i]@Wb, 32-j z tiles, reg-prefetched ----
    {
        int jl = t >> 4, hs = t & 15;
        float4 pf0, pf1; u16x8 pfu;
        if (f32) {
            const float* zrow = (const float*)z + (size_t)i * N * CZ;
            pf0 = *(const float4*)&zrow[t * 4];
            pf1 = *(const float4*)&zrow[(t + 512) * 4];
        } else {
            const unsigned short* zrow = (const unsigned short*)z + (size_t)i * N * CZ;
            pfu = *(const u16x8*)&zrow[t * 8];
        }
        for (int jt = 0; jt < 16; ++jt) {
            __syncthreads();             // previous tile fully consumed
            if (f32) {
                int f0 = t * 4, f1 = (t + 512) * 4;
                *(float4*)&U[(f0 >> 7) * 132 + (f0 & 127)] = pf0;
                *(float4*)&U[(f1 >> 7) * 132 + (f1 & 127)] = pf1;
            } else {
                int flat = t * 8; int row = flat >> 7, col = flat & 127;
                float4 lo = {bfu(pfu[0]), bfu(pfu[1]), bfu(pfu[2]), bfu(pfu[3])};
                float4 hi = {bfu(pfu[4]), bfu(pfu[5]), bfu(pfu[6]), bfu(pfu[7])};
                *(float4*)&U[row * 132 + col] = lo;
                *(float4*)&U[row * 132 + col + 4] = hi;
            }
            __syncthreads();
            if (jt < 15) {               // issue next tile loads (latency hidden)
                if (f32) {
                    const float* zrow = (const float*)z + ((size_t)i * N + (jt + 1) * 32) * CZ;
                    pf0 = *(const float4*)&zrow[t * 4];
                    pf1 = *(const float4*)&zrow[(t + 512) * 4];
                } else {
                    const unsigned short* zrow =
                        (const unsigned short*)z + ((size_t)i * N + (jt + 1) * 32) * CZ;
                    pfu = *(const u16x8*)&zrow[t * 8];
                }
            }
            if (hs < H) {
                float acc = bbL[hs];
                #pragma unroll 8
                for (int c = 0; c < CZ; ++c)
                    acc += U[jl * 132 + c] * WbL[c * H + hs];
                attL[hs * N + jt * 32 + jl] = acc;
            }
        }
    }
    __syncthreads();

    // ---- Phase B: logits, thread = key index j; kT/kpT lane-coalesced ----
    {
        int j = t;
        float mj = ld(mask, j, f32);
        float mterm = 100000.0f * (miS * mj - 1.0f);
        const float* kTj  = kT + j;
        const float* kpTj = kpT + j;
        float bj[H];
        #pragma unroll
        for (int h = 0; h < H; ++h) bj[h] = attL[h * N + j];
        for (int h = 0; h < H; ++h) {
            float qk = 0.f;
            #pragma unroll
            for (int d = 0; d < 16; ++d)
                qk += qL[h * 16 + d] * kTj[(h * 16 + d) * 512];
            float pt = 0.f;
            #pragma unroll
            for (int p = 0; p < 4; ++p) {
                float dx = qpL[h*12 + p*3 + 0] - kpTj[(h*12 + p*3 + 0) * 512];
                float dy = qpL[h*12 + p*3 + 1] - kpTj[(h*12 + p*3 + 1) * 512];
                float dz = qpL[h*12 + p*3 + 2] - kpTj[(h*12 + p*3 + 2) * 512];
                pt += dx * dx + dy * dy + dz * dz;
            }
            attL[h * N + j] = qk * 0.14433756729740643f     // sqrt(1/48)
                            + 0.5773502691896258f * bj[h]   // sqrt(1/3)
                            - 0.5f * hwL[h] * pt + mterm;
        }
    }
    __syncthreads();

    // ---- Phase C: softmax per head (one wave per head) ----
    {
        int w = t >> 6, l = t & 63;
        for (int h = w; h < H; h += 8) {
            float av[8];
            #pragma unroll
            for (int kk = 0; kk < 8; ++kk) av[kk] = attL[h * N + kk * 64 + l];
            float m = av[0];
            #pragma unroll
            for (int kk = 1; kk < 8; ++kk) m = fmaxf(m, av[kk]);
            for (int off = 1; off < 64; off <<= 1) m = fmaxf(m, __shfl_xor(m, off));
            float ssum = 0.f;
            #pragma unroll
            for (int kk = 0; kk < 8; ++kk) { av[kk] = __expf(av[kk] - m); ssum += av[kk]; }
            for (int off = 1; off < 64; off <<= 1) ssum += __shfl_xor(ssum, off);
            float inv = 1.0f / ssum;
            #pragma unroll
            for (int kk = 0; kk < 8; ++kk) attL[h * N + kk * 64 + l] = av[kk] * inv;
        }
    }
    __syncthreads();

    // ---- Phase D1: o = a@v (192 thr), o_pt + inv-frame + norm (96 thr) ----
    if (t < 192) {
        int h = t >> 4, d = t & 15;
        float acc = 0.f;
        for (int j = 0; j < N; ++j) acc += attL[h * N + j] * v[j * 192 + h * 16 + d];
        unsigned int pe = split_bf16(acc);
        catH[i * KC + t] = (unsigned short)pe;
        catL[i * KC + t] = (unsigned short)(pe >> 16);
    } else if (t < 288) {
        int hp = t - 192, h = hp >> 3, p = hp & 7;
        float ax = 0, ay = 0, az = 0;
        for (int j = 0; j < N; ++j) {
            float a_ = attL[h * N + j];
            int b2 = j * 288 + h * 24 + p * 3;
            ax += a_ * vp[b2]; ay += a_ * vp[b2 + 1]; az += a_ * vp[b2 + 2];
        }
        float gx = ax - TL[0], gy = ay - TL[1], gz = az - TL[2];
        float lx = RL[0]*gx + RL[3]*gy + RL[6]*gz;   // R^T
        float ly = RL[1]*gx + RL[4]*gy + RL[7]*gz;
        float lz = RL[2]*gx + RL[5]*gy + RL[8]*gz;
        float nrm = sqrtf(lx*lx + ly*ly + lz*lz + 1e-8f);
        unsigned int pe;
        pe = split_bf16(lx);
        catH[i * KC + 192 + hp] = (unsigned short)pe;
        catL[i * KC + 192 + hp] = (unsigned short)(pe >> 16);
        pe = split_bf16(ly);
        catH[i * KC + 288 + hp] = (unsigned short)pe;
        catL[i * KC + 288 + hp] = (unsigned short)(pe >> 16);
        pe = split_bf16(lz);
        catH[i * KC + 384 + hp] = (unsigned short)pe;
        catL[i * KC + 384 + hp] = (unsigned short)(pe >> 16);
        pe = split_bf16(nrm);
        catH[i * KC + 480 + hp] = (unsigned short)pe;
        catL[i * KC + 480 + hp] = (unsigned short)(pe >> 16);
    }

    // ---- Phase D2: o_pair = a @ z[i]  (all 512 threads, 4 j-quarters) ----
    {
        int quarter = t >> 7, c = t & 127;
        float pacc[H];
        #pragma unroll
        for (int h = 0; h < H; ++h) pacc[h] = 0.f;
        int j0 = quarter * 128;
        if (f32) {
            const float* zp = (const float*)z + ((size_t)i * N + j0) * CZ + c;
            for (int j = 0; j < 128; ++j) {
                float zc = zp[j * CZ];
                #pragma unroll
                for (int h = 0; h < H; ++h) pacc[h] += attL[h * N + j0 + j] * zc;
            }
        } else {
            const unsigned short* zp =
                (const unsigned short*)z + ((size_t)i * N + j0) * CZ + c;
            for (int j = 0; j < 128; ++j) {
                float zc = bfu(zp[j * CZ]);
                #pragma unroll
                for (int h = 0; h < H; ++h) pacc[h] += attL[h * N + j0 + j] * zc;
            }
        }
        __syncthreads();   // U free (zT dead since Phase A)
        #pragma unroll
        for (int h = 0; h < H; ++h) U[quarter * (H * CZ) + h * CZ + c] = pacc[h];
    }
    __syncthreads();
    for (int idx = t; idx < H * CZ; idx += 512) {
        float vsum = U[idx] + U[1536 + idx] + U[3072 + idx] + U[4608 + idx];
        unsigned int pe = split_bf16(vsum);
        catH[i * KC + 576 + idx] = (unsigned short)pe;
        catL[i * KC + 576 + idx] = (unsigned short)(pe >> 16);
    }
}

// ---------------------------------------------------------------------------
// K4: final_gemm — out = cat @ Wout + bout, pure load+MFMA.
// Tile 16x64: 4 waves, no LDS/barriers/VALU in K-loop. Grid (16,32) = 512
// blocks = 2 blocks/CU.
// ---------------------------------------------------------------------------
__global__ void final_gemm(const unsigned short* AH, const unsigned short* AL,
                           const unsigned short* BTh, const unsigned short* BTl,
                           const void* bout, void* out, const void* s)
{
    __shared__ int flag;
    int t = threadIdx.x;               // 256
    int bn = blockIdx.x;               // 16 col tiles of 64
    int bm = blockIdx.y;               // 32 row tiles of 16
    if (t == 0) flag = sniff_f32((const unsigned short*)s);
    __syncthreads();
    int f32 = flag;

    int w  = t >> 6, l = t & 63;
    int lr = l & 15, lq = l >> 4;

    int arow = bm * 16 + lr;
    int bcol = bn * 64 + w * 16 + lr;
    const unsigned short* ah_p = AH + (size_t)arow * KC;
    const unsigned short* al_p = AL + (size_t)arow * KC;
    const unsigned short* bh_p = BTh + (size_t)bcol * KC;
    const unsigned short* bl_p = BTl + (size_t)bcol * KC;

    f32x4 acc = {0.f, 0.f, 0.f, 0.f};
    #pragma unroll 4
    for (int kt = 0; kt < KC / 32; ++kt) {
        int kk = kt * 32 + lq * 8;
        bf16x8 a_h = *(const bf16x8*)(ah_p + kk);
        bf16x8 a_l = *(const bf16x8*)(al_p + kk);
        bf16x8 b_h = *(const bf16x8*)(bh_p + kk);
        bf16x8 b_l = *(const bf16x8*)(bl_p + kk);
        acc = __builtin_amdgcn_mfma_f32_16x16x32_bf16(a_h, b_h, acc, 0, 0, 0);
        acc = __builtin_amdgcn_mfma_f32_16x16x32_bf16(a_h, b_l, acc, 0, 0, 0);
        acc = __builtin_amdgcn_mfma_f32_16x16x32_bf16(a_l, b_h, acc, 0, 0, 0);
    }

    int row0 = bm * 16 + lq * 4;
    float bv = ld(bout, bcol, f32);
    if (f32) {
        float* o = (float*)out;
        #pragma unroll
        for (int r = 0; r < 4; ++r) o[(row0 + r) * CS + bcol] = acc[r] + bv;
    } else {
        __hip_bfloat16* o = (__hip_bfloat16*)out;
        #pragma unroll
        for (int r = 0; r < 4; ++r)
            o[(row0 + r) * CS + bcol] = __float2bfloat16(acc[r] + bv);
    }
}

extern "C" void kernel_launch(void* const* d_in, const int* in_sizes, int n_in,
                              void* d_out, int out_size, void* d_ws, size_t ws_size,
                              hipStream_t stream)
{
    const void* s      = d_in[0];
    const void* z      = d_in[1];
    const void* rot    = d_in[2];
    const void* trans  = d_in[3];
    const void* mask   = d_in[4];
    const void* Wq     = d_in[5];  const void* bq   = d_in[6];
    const void* Wkv    = d_in[7];  const void* bkv  = d_in[8];
    const void* Wqp    = d_in[9];  const void* bqp  = d_in[10];
    const void* Wkvp   = d_in[11]; const void* bkvp = d_in[12];
    const void* Wb     = d_in[13]; const void* bb   = d_in[14];
    const void* head_w = d_in[15];
    const void* Wout   = d_in[16]; const void* bout = d_in[17];

    float* w    = (float*)d_ws;
    float* q    = w;                    // 512*192
    float* kT   = q   + 98304;          // [192][512] transposed
    float* v    = kT  + 98304;          // 512*192
    float* qp   = v   + 98304;          // 512*144
    float* kpT  = qp  + 73728;          // [144][512] transposed
    float* vp   = kpT + 73728;          // 512*288
    float* rawP = vp  + 147456;         // 512*1152
    unsigned short* sH   = (unsigned short*)(rawP + 589824);  // 512*1024
    unsigned short* sL   = sH   + 524288;
    unsigned short* catH = sL   + 524288;                     // 512*2112
    unsigned short* catL = catH + 1081344;
    unsigned short* WcTh = catL + 1081344;                    // 1152*1024
    unsigned short* WcTl = WcTh + 1179648;
    unsigned short* WoTh = WcTl + 1179648;                    // 1024*2112
    unsigned short* WoTl = WoTh + 2162688;
    // total ws use ~= 24.5 MB
    (void)ws_size; (void)in_sizes; (void)n_in; (void)out_size;

    prep_w    <<<3776, 256, 0, stream>>>(Wq, Wkv, Wqp, Wkvp, Wout, s,
                                         WcTh, WcTl, WoTh, WoTl, sH, sL);
    proj_gemm <<<dim3(18, 32), 256, 0, stream>>>(sH, sL, WcTh, WcTl, rawP);
    proj_post <<<512, 576, 0, stream>>>(rawP, bq, bkv, bqp, bkvp, rot, trans, s,
                                        q, kT, v, qp, kpT, vp);
    attn_fused<<<512, 512, 0, stream>>>(q, kT, v, qp, kpT, vp, z, Wb, bb, head_w, mask,
                                        rot, trans, s, catH, catL);
    final_gemm<<<dim3(16, 32), 256, 0, stream>>>(catH, catL, WoTh, WoTl, bout,
                                                 d_out, s);
}